// Round 9
// baseline (213.525 us; speedup 1.0000x reference)
//
#include <hip/hip_runtime.h>
#include <hip/hip_fp16.h>

#define DIM 256
#define NC 16
#define NG 1000
#define CHUNK 6250      // 512 * 6250 = 3.2M exactly -> 1 chunk per block
#define NBLK 512
#define FT 1024
#define HBLK 1024       // hidden: blocks
#define HWAVES (HBLK * 4)

// ---------------------------------------------------------------------------
// K1: hidden[n][c] = dot(x[n], W[:,c]) + b[c], stored f16.
// ZERO LDS, ZERO BARRIERS. One wave per node per step:
//   - W in VGPRs: lane l permanently holds W[4l..4l+3][0..15] (64 regs).
//   - x: one coalesced 1KB wave-read per node (lane l gets x[n][4l..4l+3]).
//     4-node software pipeline with named buffers (static indexing only).
//   - per node: 64 FMA/lane -> p[16]; class-halving butterfly: at each level
//     exchange the class-half you discard (8+4+2+1 shfl over xor32/16/8/4),
//     then xor1+xor2 scalar reduce. Lane 4k ends with class k; +bias, f16
//     store. 17 shfl + 17 add per node.
// ---------------------------------------------------------------------------
__device__ __forceinline__ void hid_node(const float4 xv, const float w[4][NC],
                                         float bias, int lane, int node, int N,
                                         __half* __restrict__ hidden) {
    float p[NC];
#pragma unroll
    for (int c = 0; c < NC; ++c)
        p[c] = fmaf(xv.x, w[0][c],
               fmaf(xv.y, w[1][c],
               fmaf(xv.z, w[2][c], xv.w * w[3][c])));

    // level 1: xor 32, keep 8 classes
    const int hi1 = (lane & 32) ? 8 : 0;
    float q[8];
#pragma unroll
    for (int c = 0; c < 8; ++c)
        q[c] = p[c + hi1] + __shfl_xor(p[c + (hi1 ^ 8)], 32);
    // level 2: xor 16, keep 4
    const int hi2 = (lane & 16) ? 4 : 0;
    float r[4];
#pragma unroll
    for (int c = 0; c < 4; ++c)
        r[c] = q[c + hi2] + __shfl_xor(q[c + (hi2 ^ 4)], 16);
    // level 3: xor 8, keep 2
    const int hi3 = (lane & 8) ? 2 : 0;
    float s[2];
#pragma unroll
    for (int c = 0; c < 2; ++c)
        s[c] = r[c + hi3] + __shfl_xor(r[c + (hi3 ^ 2)], 8);
    // level 4: xor 4, keep 1
    const int hi4 = (lane & 4) ? 1 : 0;
    float t0 = s[hi4] + __shfl_xor(s[hi4 ^ 1], 4);
    // remaining lanes (bits 0,1) hold disjoint dim-slices of same class
    t0 += __shfl_xor(t0, 1);
    t0 += __shfl_xor(t0, 2);

    if ((lane & 3) == 0 && node < N)
        hidden[(size_t)node * NC + ((lane >> 2) & 15)] = __float2half(t0 + bias);
}

__global__ void __launch_bounds__(256) hidden_kernel(
    const float* __restrict__ x, const float* __restrict__ W,
    const float* __restrict__ b, __half* __restrict__ hidden, int N) {
    const int lane = threadIdx.x & 63;
    const int wave = (blockIdx.x * blockDim.x + threadIdx.x) >> 6;

    // lane l holds W[4l..4l+3][*] (one-time scattered read, 16 x float4)
    float w[4][NC];
#pragma unroll
    for (int rr = 0; rr < 4; ++rr)
#pragma unroll
        for (int c4 = 0; c4 < 4; ++c4) {
            float4 t = *(const float4*)(W + (size_t)(4 * lane + rr) * NC + 4 * c4);
            w[rr][4 * c4 + 0] = t.x;
            w[rr][4 * c4 + 1] = t.y;
            w[rr][4 * c4 + 2] = t.z;
            w[rr][4 * c4 + 3] = t.w;
        }
    const float bias = b[(lane >> 2) & 15];

    const int S = HWAVES * 4;   // nodes per pipeline step over all waves
#define LDX(n) (*(const float4*)(x + (size_t)min((n), N - 1) * DIM + 4 * lane))

    int n = wave * 4;
    if (n >= N) return;
    float4 a0 = LDX(n), a1 = LDX(n + 1), a2 = LDX(n + 2), a3 = LDX(n + 3);

    for (; n < N; n += S) {
        const int m = n + S;
        float4 b0, b1, b2, b3;
        if (m < N) {                     // prefetch next group (wave-uniform)
            b0 = LDX(m); b1 = LDX(m + 1); b2 = LDX(m + 2); b3 = LDX(m + 3);
        }
        hid_node(a0, w, bias, lane, n,     N, hidden);
        hid_node(a1, w, bias, lane, n + 1, N, hidden);
        hid_node(a2, w, bias, lane, n + 2, N, hidden);
        hid_node(a3, w, bias, lane, n + 3, N, hidden);
        a0 = b0; a1 = b1; a2 = b2; a3 = b3;
    }
#undef LDX
}

// ---------------------------------------------------------------------------
// K2: node -> graph id (searchsorted 'right' over sorted ed_idx)
// ---------------------------------------------------------------------------
__global__ void seg_kernel(const int* __restrict__ ed_idx,
                           int* __restrict__ node_seg, int N, int G) {
    int n = blockIdx.x * blockDim.x + threadIdx.x;
    if (n >= N) return;
    int lo = 0, hi = G;
    while (lo < hi) {
        int mid = (lo + hi) >> 1;
        if (ed_idx[mid] <= n) lo = mid + 1; else hi = mid;
    }
    node_seg[n] = lo;
}

// ---------------------------------------------------------------------------
// K3: fused hist + in-LDS counting sort + register pooling (unchanged:
// one 6250-edge chunk per block, node_seg direct lookup, prefetch-pipelined
// pool gathers, coalesced partial slice per block).
// ---------------------------------------------------------------------------
__global__ void __launch_bounds__(FT) gcn_pool_kernel(
    const int* __restrict__ rows, const int* __restrict__ cols,
    const float* __restrict__ vals, const __half* __restrict__ hidden,
    const int* __restrict__ node_seg, float* __restrict__ partials, int nE) {
    __shared__ unsigned hist[NG];
    __shared__ unsigned cursor[NG];
    __shared__ unsigned wsum[FT / 64];
    __shared__ unsigned short raw_g[CHUNK];
    __shared__ uint2 sorted[CHUNK];

    const int t = threadIdx.x, lane = t & 63, wid = t >> 6;
    const int beg = blockIdx.x * CHUNK;
    const int cnt = min(nE - beg, CHUNK);

    for (int i = t; i < NG; i += FT) hist[i] = 0u;
    __syncthreads();

    for (int i = t; i < cnt; i += 2 * FT) {
        int i2 = i + FT;
        bool ok2 = i2 < cnt;
        int r1 = rows[beg + i];
        int r2 = rows[beg + (ok2 ? i2 : i)];
        int g1 = node_seg[r1];
        int g2 = node_seg[r2];
        raw_g[i] = (unsigned short)g1;
        if (g1 < NG) atomicAdd(&hist[g1], 1u);
        if (ok2) {
            raw_g[i2] = (unsigned short)g2;
            if (g2 < NG) atomicAdd(&hist[g2], 1u);
        }
    }
    __syncthreads();

    unsigned v = (t < NG) ? hist[t] : 0u;
    unsigned inc = v;
#pragma unroll
    for (int d = 1; d < 64; d <<= 1) {
        unsigned u = __shfl_up(inc, d);
        if (lane >= d) inc += u;
    }
    if (lane == 63) wsum[wid] = inc;
    __syncthreads();
    if (wid == 0) {
        unsigned v2 = (lane < FT / 64) ? wsum[lane] : 0u;
        unsigned inc2 = v2;
#pragma unroll
        for (int d = 1; d < FT / 64; d <<= 1) {
            unsigned u = __shfl_up(inc2, d);
            if (lane >= d) inc2 += u;
        }
        if (lane < FT / 64) wsum[lane] = inc2 - v2;
    }
    __syncthreads();
    unsigned myBeg = wsum[wid] + inc - v;
    if (t < NG) cursor[t] = myBeg;
    __syncthreads();

    for (int i = t; i < cnt; i += FT) {
        int g = raw_g[i];
        if (g < NG) {
            unsigned pos = atomicAdd(&cursor[g], 1u);
            sorted[pos] = make_uint2((unsigned)cols[beg + i],
                                     __float_as_uint(vals[beg + i]));
        }
    }
    __syncthreads();

    float acc[NC];
#pragma unroll
    for (int c = 0; c < NC; ++c) acc[c] = 0.f;

    if (t < NG && v) {
        unsigned i = myBeg, end = myBeg + v;
        uint2 cv = sorted[i];
        uint4 h0 = *(const uint4*)(hidden + (size_t)cv.x * NC);
        uint4 h1 = *(const uint4*)(hidden + (size_t)cv.x * NC + 8);
        while (i < end) {
            unsigned nx = i + 1;
            uint2 cvn = cv;
            uint4 h0n = h0, h1n = h1;
            if (nx < end) {
                cvn = sorted[nx];
                h0n = *(const uint4*)(hidden + (size_t)cvn.x * NC);
                h1n = *(const uint4*)(hidden + (size_t)cvn.x * NC + 8);
            }
            float vv = __uint_as_float(cv.y);
            const __half2* q0 = (const __half2*)&h0;
            const __half2* q1 = (const __half2*)&h1;
#pragma unroll
            for (int k = 0; k < 4; ++k) {
                float2 f0 = __half22float2(q0[k]);
                float2 f1 = __half22float2(q1[k]);
                acc[2 * k]         = fmaf(vv, f0.x, acc[2 * k]);
                acc[2 * k + 1]     = fmaf(vv, f0.y, acc[2 * k + 1]);
                acc[8 + 2 * k]     = fmaf(vv, f1.x, acc[8 + 2 * k]);
                acc[8 + 2 * k + 1] = fmaf(vv, f1.y, acc[8 + 2 * k + 1]);
            }
            cv = cvn; h0 = h0n; h1 = h1n; i = nx;
        }
    }

    if (t < NG) {
        float4* p = (float4*)(partials + ((size_t)blockIdx.x * NG + t) * NC);
        p[0] = make_float4(acc[0], acc[1], acc[2], acc[3]);
        p[1] = make_float4(acc[4], acc[5], acc[6], acc[7]);
        p[2] = make_float4(acc[8], acc[9], acc[10], acc[11]);
        p[3] = make_float4(acc[12], acc[13], acc[14], acc[15]);
    }
}

// ---------------------------------------------------------------------------
// K4: fold partials[NBLK][NG*NC] into out; blockIdx.y picks 64 slices.
// ---------------------------------------------------------------------------
__global__ void reduce_kernel(const float* __restrict__ partials,
                              float* __restrict__ out) {
    int i = blockIdx.x * blockDim.x + threadIdx.x;
    if (i >= NG * NC) return;
    const int per = NBLK / 8;  // 64
    const float* p = partials + (size_t)(blockIdx.y * per) * (NG * NC) + i;
    float s0 = 0.f, s1 = 0.f, s2 = 0.f, s3 = 0.f;
#pragma unroll 4
    for (int k = 0; k < per; k += 4) {
        s0 += p[(size_t)(k + 0) * (NG * NC)];
        s1 += p[(size_t)(k + 1) * (NG * NC)];
        s2 += p[(size_t)(k + 2) * (NG * NC)];
        s3 += p[(size_t)(k + 3) * (NG * NC)];
    }
    atomicAdd(&out[i], (s0 + s1) + (s2 + s3));
}

extern "C" void kernel_launch(void* const* d_in, const int* in_sizes, int n_in,
                              void* d_out, int out_size, void* d_ws, size_t ws_size,
                              hipStream_t stream) {
    const float* x      = (const float*)d_in[0];
    const int*   ed_idx = (const int*)  d_in[1];
    const int*   rows   = (const int*)  d_in[2];
    const int*   cols   = (const int*)  d_in[3];
    const float* vals   = (const float*)d_in[4];
    const float* W      = (const float*)d_in[5];
    const float* b      = (const float*)d_in[6];
    float* out = (float*)d_out;

    int N  = in_sizes[0] / DIM;   // 100000
    int G  = in_sizes[1];         // 1000
    int nE = in_sizes[2];         // 3200000

    size_t off = 0;
    auto alloc = [&](size_t bytes, size_t align) {
        off = (off + align - 1) / align * align;
        size_t r = off; off += bytes; return r;
    };
    __half* hidden   = (__half*)((char*)d_ws + alloc((size_t)N * NC * 2, 16));
    int*    node_seg = (int*)   ((char*)d_ws + alloc((size_t)N * 4, 16));
    float*  partials = (float*) ((char*)d_ws + alloc((size_t)NBLK * NG * NC * 4, 16));
    (void)ws_size;

    hipMemsetAsync(d_out, 0, (size_t)out_size * sizeof(float), stream);

    seg_kernel<<<(N + 255) / 256, 256, 0, stream>>>(ed_idx, node_seg, N, G);
    hidden_kernel<<<HBLK, 256, 0, stream>>>(x, W, b, hidden, N);
    gcn_pool_kernel<<<NBLK, FT, 0, stream>>>(rows, cols, vals, hidden,
                                             node_seg, partials, nE);
    dim3 rg((NG * NC + 255) / 256, 8);
    reduce_kernel<<<rg, 256, 0, stream>>>(partials, out);
}

// Round 11
// 92.702 us; speedup vs baseline: 2.3033x; 2.3033x over previous
//
#include <hip/hip_runtime.h>
#include <hip/hip_fp16.h>

#define DIM 256
#define NC 16
#define NG 1000
#define CHUNK 6250      // 512 * 6250 = 3.2M exactly -> 1 chunk per block
#define NBLK 512
#define FT 1024

typedef _Float16 f16x8 __attribute__((ext_vector_type(8)));
typedef float f32x4 __attribute__((ext_vector_type(4)));

// ---------------------------------------------------------------------------
// K1: hidden[n][c] = dot(x[n], W[:,c]) + b[c], stored f16 — via MFMA.
// One wave per 16-node tile; K=256 as 8 x mfma_f32_16x16x32_f16.
//   A: lane l holds x[node0+(l&15)][s*32+(l>>4)*8 .. +8] (2 float4 loads,
//      scalar (_Float16) casts -> packed fragment). x read exactly once.
//   B: lane l holds W[s*32+(l>>4)*8+j][l&15] f16 (8 frags = 32 VGPR, once).
//   C: col=lane&15 (class), row=(lane>>4)*4+j (node) [m89-verified layout].
// K-reduction in the matrix pipe: zero shuffles, zero LDS, zero barriers,
// no per-FMA W delivery (kills rounds 2-9's failure modes).
// ---------------------------------------------------------------------------
__global__ void __launch_bounds__(256) hidden_kernel(
    const float* __restrict__ x, const float* __restrict__ W,
    const float* __restrict__ b, __half* __restrict__ hidden, int N) {
    const int lane = threadIdx.x & 63;
    const int wave = (blockIdx.x * blockDim.x + threadIdx.x) >> 6;
    const int m = lane & 15;        // A row (node in tile) / B col (class)
    const int kb = lane >> 4;       // k-group

    const int nTiles = (N + 15) >> 4;
    if (wave >= nTiles) return;

    // B fragments (one-time; same for all waves -> L2 broadcast)
    f16x8 wf[8];
#pragma unroll
    for (int s = 0; s < 8; ++s) {
        const float* wp = W + (size_t)(s * 32 + kb * 8) * NC + m;
        wf[s] = (f16x8){(_Float16)wp[0 * NC], (_Float16)wp[1 * NC],
                        (_Float16)wp[2 * NC], (_Float16)wp[3 * NC],
                        (_Float16)wp[4 * NC], (_Float16)wp[5 * NC],
                        (_Float16)wp[6 * NC], (_Float16)wp[7 * NC]};
    }
    const float bias = b[m];

    const int node0 = wave * 16;
    const int row = min(node0 + m, N - 1);
    const float* xp = x + (size_t)row * DIM + kb * 8;

    float4 ra[8], rb[8];
#pragma unroll
    for (int s = 0; s < 8; ++s) {
        ra[s] = *(const float4*)(xp + s * 32);
        rb[s] = *(const float4*)(xp + s * 32 + 4);
    }

    f32x4 acc = {0.f, 0.f, 0.f, 0.f};
#pragma unroll
    for (int s = 0; s < 8; ++s) {
        f16x8 af = (f16x8){(_Float16)ra[s].x, (_Float16)ra[s].y,
                           (_Float16)ra[s].z, (_Float16)ra[s].w,
                           (_Float16)rb[s].x, (_Float16)rb[s].y,
                           (_Float16)rb[s].z, (_Float16)rb[s].w};
        acc = __builtin_amdgcn_mfma_f32_16x16x32_f16(af, wf[s], acc, 0, 0, 0);
    }

#pragma unroll
    for (int j = 0; j < 4; ++j) {
        int node = node0 + kb * 4 + j;
        if (node < N)
            hidden[(size_t)node * NC + m] = __float2half(acc[j] + bias);
    }
}

// ---------------------------------------------------------------------------
// K2: node -> graph id (searchsorted 'right' over sorted ed_idx)
// ---------------------------------------------------------------------------
__global__ void seg_kernel(const int* __restrict__ ed_idx,
                           int* __restrict__ node_seg, int N, int G) {
    int n = blockIdx.x * blockDim.x + threadIdx.x;
    if (n >= N) return;
    int lo = 0, hi = G;
    while (lo < hi) {
        int mid = (lo + hi) >> 1;
        if (ed_idx[mid] <= n) lo = mid + 1; else hi = mid;
    }
    node_seg[n] = lo;
}

// ---------------------------------------------------------------------------
// K3: fused hist + in-LDS counting sort + register pooling (unchanged:
// one 6250-edge chunk per block, node_seg direct lookup, prefetch-pipelined
// pool gathers, coalesced partial slice per block).
// ---------------------------------------------------------------------------
__global__ void __launch_bounds__(FT) gcn_pool_kernel(
    const int* __restrict__ rows, const int* __restrict__ cols,
    const float* __restrict__ vals, const __half* __restrict__ hidden,
    const int* __restrict__ node_seg, float* __restrict__ partials, int nE) {
    __shared__ unsigned hist[NG];
    __shared__ unsigned cursor[NG];
    __shared__ unsigned wsum[FT / 64];
    __shared__ unsigned short raw_g[CHUNK];
    __shared__ uint2 sorted[CHUNK];

    const int t = threadIdx.x, lane = t & 63, wid = t >> 6;
    const int beg = blockIdx.x * CHUNK;
    const int cnt = min(nE - beg, CHUNK);

    for (int i = t; i < NG; i += FT) hist[i] = 0u;
    __syncthreads();

    for (int i = t; i < cnt; i += 2 * FT) {
        int i2 = i + FT;
        bool ok2 = i2 < cnt;
        int r1 = rows[beg + i];
        int r2 = rows[beg + (ok2 ? i2 : i)];
        int g1 = node_seg[r1];
        int g2 = node_seg[r2];
        raw_g[i] = (unsigned short)g1;
        if (g1 < NG) atomicAdd(&hist[g1], 1u);
        if (ok2) {
            raw_g[i2] = (unsigned short)g2;
            if (g2 < NG) atomicAdd(&hist[g2], 1u);
        }
    }
    __syncthreads();

    unsigned v = (t < NG) ? hist[t] : 0u;
    unsigned inc = v;
#pragma unroll
    for (int d = 1; d < 64; d <<= 1) {
        unsigned u = __shfl_up(inc, d);
        if (lane >= d) inc += u;
    }
    if (lane == 63) wsum[wid] = inc;
    __syncthreads();
    if (wid == 0) {
        unsigned v2 = (lane < FT / 64) ? wsum[lane] : 0u;
        unsigned inc2 = v2;
#pragma unroll
        for (int d = 1; d < FT / 64; d <<= 1) {
            unsigned u = __shfl_up(inc2, d);
            if (lane >= d) inc2 += u;
        }
        if (lane < FT / 64) wsum[lane] = inc2 - v2;
    }
    __syncthreads();
    unsigned myBeg = wsum[wid] + inc - v;
    if (t < NG) cursor[t] = myBeg;
    __syncthreads();

    for (int i = t; i < cnt; i += FT) {
        int g = raw_g[i];
        if (g < NG) {
            unsigned pos = atomicAdd(&cursor[g], 1u);
            sorted[pos] = make_uint2((unsigned)cols[beg + i],
                                     __float_as_uint(vals[beg + i]));
        }
    }
    __syncthreads();

    float acc[NC];
#pragma unroll
    for (int c = 0; c < NC; ++c) acc[c] = 0.f;

    if (t < NG && v) {
        unsigned i = myBeg, end = myBeg + v;
        uint2 cv = sorted[i];
        uint4 h0 = *(const uint4*)(hidden + (size_t)cv.x * NC);
        uint4 h1 = *(const uint4*)(hidden + (size_t)cv.x * NC + 8);
        while (i < end) {
            unsigned nx = i + 1;
            uint2 cvn = cv;
            uint4 h0n = h0, h1n = h1;
            if (nx < end) {
                cvn = sorted[nx];
                h0n = *(const uint4*)(hidden + (size_t)cvn.x * NC);
                h1n = *(const uint4*)(hidden + (size_t)cvn.x * NC + 8);
            }
            float vv = __uint_as_float(cv.y);
            const __half2* q0 = (const __half2*)&h0;
            const __half2* q1 = (const __half2*)&h1;
#pragma unroll
            for (int k = 0; k < 4; ++k) {
                float2 f0 = __half22float2(q0[k]);
                float2 f1 = __half22float2(q1[k]);
                acc[2 * k]         = fmaf(vv, f0.x, acc[2 * k]);
                acc[2 * k + 1]     = fmaf(vv, f0.y, acc[2 * k + 1]);
                acc[8 + 2 * k]     = fmaf(vv, f1.x, acc[8 + 2 * k]);
                acc[8 + 2 * k + 1] = fmaf(vv, f1.y, acc[8 + 2 * k + 1]);
            }
            cv = cvn; h0 = h0n; h1 = h1n; i = nx;
        }
    }

    if (t < NG) {
        float4* p = (float4*)(partials + ((size_t)blockIdx.x * NG + t) * NC);
        p[0] = make_float4(acc[0], acc[1], acc[2], acc[3]);
        p[1] = make_float4(acc[4], acc[5], acc[6], acc[7]);
        p[2] = make_float4(acc[8], acc[9], acc[10], acc[11]);
        p[3] = make_float4(acc[12], acc[13], acc[14], acc[15]);
    }
}

// ---------------------------------------------------------------------------
// K4: fold partials[NBLK][NG*NC] into out; blockIdx.y picks 64 slices.
// ---------------------------------------------------------------------------
__global__ void reduce_kernel(const float* __restrict__ partials,
                              float* __restrict__ out) {
    int i = blockIdx.x * blockDim.x + threadIdx.x;
    if (i >= NG * NC) return;
    const int per = NBLK / 8;  // 64
    const float* p = partials + (size_t)(blockIdx.y * per) * (NG * NC) + i;
    float s0 = 0.f, s1 = 0.f, s2 = 0.f, s3 = 0.f;
#pragma unroll 4
    for (int k = 0; k < per; k += 4) {
        s0 += p[(size_t)(k + 0) * (NG * NC)];
        s1 += p[(size_t)(k + 1) * (NG * NC)];
        s2 += p[(size_t)(k + 2) * (NG * NC)];
        s3 += p[(size_t)(k + 3) * (NG * NC)];
    }
    atomicAdd(&out[i], (s0 + s1) + (s2 + s3));
}

extern "C" void kernel_launch(void* const* d_in, const int* in_sizes, int n_in,
                              void* d_out, int out_size, void* d_ws, size_t ws_size,
                              hipStream_t stream) {
    const float* x      = (const float*)d_in[0];
    const int*   ed_idx = (const int*)  d_in[1];
    const int*   rows   = (const int*)  d_in[2];
    const int*   cols   = (const int*)  d_in[3];
    const float* vals   = (const float*)d_in[4];
    const float* W      = (const float*)d_in[5];
    const float* b      = (const float*)d_in[6];
    float* out = (float*)d_out;

    int N  = in_sizes[0] / DIM;   // 100000
    int G  = in_sizes[1];         // 1000
    int nE = in_sizes[2];         // 3200000

    size_t off = 0;
    auto alloc = [&](size_t bytes, size_t align) {
        off = (off + align - 1) / align * align;
        size_t r = off; off += bytes; return r;
    };
    __half* hidden   = (__half*)((char*)d_ws + alloc((size_t)N * NC * 2, 16));
    int*    node_seg = (int*)   ((char*)d_ws + alloc((size_t)N * 4, 16));
    float*  partials = (float*) ((char*)d_ws + alloc((size_t)NBLK * NG * NC * 4, 16));
    (void)ws_size;

    (void)hipMemsetAsync(d_out, 0, (size_t)out_size * sizeof(float), stream);

    seg_kernel<<<(N + 255) / 256, 256, 0, stream>>>(ed_idx, node_seg, N, G);
    int nTiles = (N + 15) / 16;                    // one wave per tile
    int hblocks = (nTiles + 3) / 4;                // 4 waves per block
    hidden_kernel<<<hblocks, 256, 0, stream>>>(x, W, b, hidden, N);
    gcn_pool_kernel<<<NBLK, FT, 0, stream>>>(rows, cols, vals, hidden,
                                             node_seg, partials, nE);
    dim3 rg((NG * NC + 255) / 256, 8);
    reduce_kernel<<<rg, 256, 0, stream>>>(partials, out);
}